// Round 9
// baseline (170.044 us; speedup 1.0000x reference)
//
#include <hip/hip_runtime.h>
#include <stdint.h>

typedef __bf16 bf16;
typedef __bf16 bf16x8 __attribute__((ext_vector_type(8)));
typedef __bf16 bf16x4 __attribute__((ext_vector_type(4)));
typedef float f32x4 __attribute__((ext_vector_type(4)));

#define MFMA16x16x32(A, B, C) __builtin_amdgcn_mfma_f32_16x16x32_bf16((A), (B), (C), 0, 0, 0)
#define SBAR() do { __builtin_amdgcn_s_barrier(); __builtin_amdgcn_sched_barrier(0); } while (0)

__device__ __forceinline__ void gload_lds16(const void* g, void* l) {
  __builtin_amdgcn_global_load_lds((const __attribute__((address_space(1))) void*)g,
                                   (__attribute__((address_space(3))) void*)l,
                                   16, 0, 0);
}

__device__ __forceinline__ float fexp2(float x) { return __builtin_amdgcn_exp2f(x); }

__device__ __forceinline__ bf16x8 cvt8(float4 a, float4 b) {
  bf16x8 o;
  o[0] = (bf16)a.x; o[1] = (bf16)a.y; o[2] = (bf16)a.z; o[3] = (bf16)a.w;
  o[4] = (bf16)b.x; o[5] = (bf16)b.y; o[6] = (bf16)b.z; o[7] = (bf16)b.w;
  return o;
}

// ---------------- x1+x2 -> bf16 (contiguous dst) ----------------
__global__ void cast_x(const float* __restrict__ x1, const float* __restrict__ x2,
                       bf16* __restrict__ out) {
  const size_t i = ((size_t)blockIdx.x * blockDim.x + threadIdx.x) * 8;
  const float* src = (i < 4194304) ? x1 + i : x2 + (i - 4194304);
  float4 a = *reinterpret_cast<const float4*>(src);
  float4 b = *reinterpret_cast<const float4*>(src + 4);
  *reinterpret_cast<bf16x8*>(out + i) = cvt8(a, b);
}

// ---------------- projection GEMM: C = A[M,512] @ W[N,512]^T ----------------
// (unchanged from r8 — perf-neutral vs r7, keep)
template <int MODE>
__global__ __launch_bounds__(256, 4) void proj_kernel(
    const bf16* __restrict__ A0, const bf16* __restrict__ A1,
    const float* __restrict__ W0, const float* __restrict__ W1,
    const float* __restrict__ W2, void* __restrict__ C0, void* __restrict__ C1,
    void* __restrict__ C2, const float* __restrict__ bias) {
  __shared__ bf16 As[3][128 * 32];
  __shared__ bf16 Bs[2][64 * 32];
  const int tid = threadIdx.x;
  const int w = tid >> 6, l = tid & 63;
  const int wr = w >> 1, wc = w & 1;
  const int lr = l & 15, lg = l >> 4;
  const int bm = blockIdx.x, bn = blockIdx.y;
  const int K = 512;

  int sel = 0, wn = bn;
  const bf16* A;
  const float* Bf;
  if constexpr (MODE == 0) {
    sel = bn >> 3;
    wn = bn & 7;
    A = (sel == 0) ? A0 : A1;
    Bf = ((sel == 0) ? W0 : (sel == 1) ? W1 : W2) + (size_t)wn * 64 * K;
  } else {
    A = A0;
    Bf = W0 + (size_t)bn * 64 * K;
  }

  const int c_row = l >> 2;
  const int c_s = l & 3;
  const int sw = (c_s ^ (c_row & 3)) * 8;

  float4 lb[2][2];
  auto issue_A = [&](int t, int bb) {
#pragma unroll
    for (int i = 0; i < 2; i++) {
      const int q = w + i * 4;
      gload_lds16(A + (size_t)(bm * 128 + q * 16 + c_row) * K + t * 32 + sw, &As[bb][q * 512]);
    }
  };
  auto issue_B = [&](int t, int s) {
    const float* pb = Bf + (size_t)(w * 16 + c_row) * K + t * 32 + c_s * 8;
    lb[s][0] = *reinterpret_cast<const float4*>(pb);
    lb[s][1] = *reinterpret_cast<const float4*>(pb + 4);
  };
  auto commit_B = [&](int s, int bb) {
    *reinterpret_cast<bf16x8*>(&Bs[bb][w * 512 + c_row * 32 + sw]) = cvt8(lb[s][0], lb[s][1]);
  };

  f32x4 acc[4][2] = {};
  const int swz = (lr & 3) * 8;

  issue_A(0, 0); issue_B(0, 0);
  issue_A(1, 1); issue_B(1, 1);
  asm volatile("s_waitcnt vmcnt(4)" ::: "memory");
  commit_B(0, 0);
  asm volatile("s_waitcnt lgkmcnt(0)" ::: "memory");
  SBAR();

  const int NT = 16;
  for (int t = 0; t < NT; t++) {
    if (t + 2 < NT) { issue_A(t + 2, (t + 2) % 3); issue_B(t + 2, t & 1); }

    bf16x8 a[4], b[2];
    const int cur = t % 3;
#pragma unroll
    for (int mi = 0; mi < 4; mi++)
      a[mi] = *reinterpret_cast<const bf16x8*>(
          &As[cur][(wr * 64 + mi * 16 + lr) * 32 + (lg * 8 ^ swz)]);
#pragma unroll
    for (int ni = 0; ni < 2; ni++)
      b[ni] = *reinterpret_cast<const bf16x8*>(
          &Bs[t & 1][(wc * 32 + ni * 16 + lr) * 32 + (lg * 8 ^ swz)]);
#pragma unroll
    for (int mi = 0; mi < 4; mi++)
#pragma unroll
      for (int ni = 0; ni < 2; ni++)
        acc[mi][ni] = MFMA16x16x32(a[mi], b[ni], acc[mi][ni]);

    if (t + 1 < NT) {
      if (t + 2 < NT) asm volatile("s_waitcnt vmcnt(4)" ::: "memory");
      else            asm volatile("s_waitcnt vmcnt(0)" ::: "memory");
      commit_B((t + 1) & 1, (t + 1) & 1);
      asm volatile("s_waitcnt lgkmcnt(0)" ::: "memory");
      SBAR();
    }
  }

#pragma unroll
  for (int mi = 0; mi < 4; mi++) {
    const int m0 = bm * 128 + wr * 64 + mi * 16 + lg * 4;
#pragma unroll
    for (int ni = 0; ni < 2; ni++) {
      const int n = wc * 32 + ni * 16 + lr;
      if constexpr (MODE == 0) {
        const int gn = wn * 64 + n;
        if (sel < 2) {
          bf16* dst = (bf16*)((sel == 0) ? C0 : C1);
          const float scale = (sel == 0) ? 0.18033688011112f : 1.0f;
#pragma unroll
          for (int r = 0; r < 4; r++) {
            const int m = m0 + r;
            size_t d = (size_t)((m >> 11) * 8 + (gn >> 6)) * 131072 + (size_t)(m & 2047) * 64 + (gn & 63);
            dst[d] = (bf16)(acc[mi][ni][r] * scale);
          }
        } else {
          bf16x4 pv;
#pragma unroll
          for (int r = 0; r < 4; r++) pv[r] = (bf16)acc[mi][ni][r];
          size_t base = ((size_t)(m0 >> 11) * 512 + gn) * 2048 + (m0 & 2047);
          *reinterpret_cast<bf16x4*>((bf16*)C2 + base) = pv;
        }
      } else {
        const int gn = bn * 64 + n;
        const float bv = bias[gn];
#pragma unroll
        for (int r = 0; r < 4; r++)
          ((float*)C0)[(size_t)(m0 + r) * 512 + gn] = acc[mi][ni][r] + bv;
      }
    }
  }
}

// ---------------- flash attention (no K/V staging: L1/L2-direct, barrier-free loop) ----
// Q: [BH][2048][64] (pre-scaled by 0.125*log2e), K: [BH][2048][64], V^T: [BH][64][2048]
// 512 thr (8 waves), 256 q-rows (32/wave), kv tiles of 64, grid 256 (4 bh per XCD).
// K/V frag reads go straight to global (K/V tile = 16KB, L1-resident per CU; all 8
// waves read the same tile). LDS holds only the per-wave P stash -> no loop barriers.
// K frags reg-double-buffered via explicit unroll-2 (no runtime-indexed frag arrays).
__global__ __launch_bounds__(512, 1) void attn_kernel(
    const bf16* __restrict__ Q, const bf16* __restrict__ Kk,
    const bf16* __restrict__ Vt, bf16* __restrict__ AO) {
  __shared__ bf16 Ps[8][32 * 64];  // 32KB per-wave P stash [32 q][64 kv]

  const int tid = threadIdx.x;
  const int w = tid >> 6, l = tid & 63;
  const int lr = l & 15, lg = l >> 4;

  // XCD-aware decode: 4 bh per XCD -> K/V L2-resident (2MB/XCD)
  const int lin = blockIdx.x;  // 0..255
  const int xcd = lin & 7;
  const int m = lin >> 3;
  const int bh = xcd * 4 + (m & 3);
  const int qb = m >> 2;  // 0..7
  const int b = bh >> 3, h = bh & 7;

  const bf16* Qb = Q + (size_t)bh * 131072;
  const bf16* Kb = Kk + (size_t)bh * 131072;
  const bf16* Vb = Vt + (size_t)bh * 131072;

  const int q0 = qb * 256 + w * 32;

  // Q fragments (B-operand): qf[i]: col q = i*16+lr, k = d = ks*32+lg*8+j
  bf16x8 qf[2][2];
#pragma unroll
  for (int i = 0; i < 2; i++)
#pragma unroll
    for (int ks = 0; ks < 2; ks++)
      qf[i][ks] = *reinterpret_cast<const bf16x8*>(
          Qb + (size_t)(q0 + i * 16 + lr) * 64 + ks * 32 + lg * 8);

  f32x4 oacc[2][4] = {};
  float lsum[2] = {0.f, 0.f};
  const int sw8 = (lr & 7) * 8;

  // K frag load: row kv = c*16+lr, col d = ks*32+lg*8 (wave covers a dense 1KB span)
  auto loadK = [&](int kv0, bf16x8 (&kb)[2][4]) {
#pragma unroll
    for (int ks = 0; ks < 2; ks++)
#pragma unroll
      for (int c = 0; c < 4; c++)
        kb[ks][c] = *reinterpret_cast<const bf16x8*>(
            Kb + (size_t)(kv0 + c * 16 + lr) * 64 + ks * 32 + lg * 8);
  };

  auto body = [&](int kv0, bf16x8 (&kb)[2][4]) {
    // S^T = K Q^T per q-frag; exp2; stash P
#pragma unroll
    for (int i = 0; i < 2; i++) {
      f32x4 st[4] = {};
#pragma unroll
      for (int ks = 0; ks < 2; ks++)
#pragma unroll
        for (int c = 0; c < 4; c++)
          st[c] = MFMA16x16x32(kb[ks][c], qf[i][ks], st[c]);
#pragma unroll
      for (int c = 0; c < 4; c++) {
        float e0 = fexp2(st[c][0]);
        float e1 = fexp2(st[c][1]);
        float e2 = fexp2(st[c][2]);
        float e3 = fexp2(st[c][3]);
        lsum[i] += (e0 + e1) + (e2 + e3);
        bf16x4 pk;
        pk[0] = (bf16)e0; pk[1] = (bf16)e1; pk[2] = (bf16)e2; pk[3] = (bf16)e3;
        *reinterpret_cast<bf16x4*>(
            &Ps[w][(i * 16 + lr) * 64 + ((c * 16 + lg * 4) ^ sw8)]) = pk;
      }
    }

    // V frags direct from global: row d = c*16+lr, col kv = ks*32+lg*8
    bf16x8 vb[2][4];
#pragma unroll
    for (int ks = 0; ks < 2; ks++)
#pragma unroll
      for (int c = 0; c < 4; c++)
        vb[ks][c] = *reinterpret_cast<const bf16x8*>(
            Vb + (size_t)(c * 16 + lr) * 2048 + kv0 + ks * 32 + lg * 8);

    // O += P @ V
#pragma unroll
    for (int i = 0; i < 2; i++)
#pragma unroll
      for (int ks = 0; ks < 2; ks++) {
        bf16x8 pa = *reinterpret_cast<const bf16x8*>(
            &Ps[w][(i * 16 + lr) * 64 + ((ks * 32 + lg * 8) ^ sw8)]);
#pragma unroll
        for (int c = 0; c < 4; c++)
          oacc[i][c] = MFMA16x16x32(pa, vb[ks][c], oacc[i][c]);
      }
  };

  bf16x8 kbA[2][4], kbB[2][4];
  loadK(0, kbA);
  for (int t = 0; t < 32; t += 2) {
    loadK((t + 1) * 64, kbB);        // prefetch odd tile (hidden under even body)
    body(t * 64, kbA);
    if (t + 2 < 32) loadK((t + 2) * 64, kbA);  // prefetch next even tile
    body((t + 1) * 64, kbB);
  }

  // row-sum reduce: lanes lr, lr+16, lr+32, lr+48 hold partials of q-row i*16+lr
#pragma unroll
  for (int i = 0; i < 2; i++) {
    lsum[i] += __shfl_xor(lsum[i], 16);
    lsum[i] += __shfl_xor(lsum[i], 32);
  }

  // normalize + write AO[b*2048+q][h*64+d]; oacc row q = i*16 + lg*4 + r
#pragma unroll
  for (int i = 0; i < 2; i++) {
#pragma unroll
    for (int r = 0; r < 4; r++) {
      const float inv = 1.f / __shfl(lsum[i], lg * 4 + r);
      const int qrow = q0 + i * 16 + lg * 4 + r;
#pragma unroll
      for (int c = 0; c < 4; c++)
        AO[(size_t)(b * 2048 + qrow) * 512 + h * 64 + c * 16 + lr] = (bf16)(oacc[i][c][r] * inv);
    }
  }
}

// ---------------- launch ----------------
extern "C" void kernel_launch(void* const* d_in, const int* in_sizes, int n_in,
                              void* d_out, int out_size, void* d_ws, size_t ws_size,
                              hipStream_t stream) {
  (void)in_sizes; (void)n_in; (void)out_size; (void)ws_size;
  const float* x1 = (const float*)d_in[0];
  const float* x2 = (const float*)d_in[1];
  const float* Wq = (const float*)d_in[2];
  const float* Wk = (const float*)d_in[3];
  const float* Wv = (const float*)d_in[4];
  const float* Wo = (const float*)d_in[5];
  const float* bo = (const float*)d_in[6];

  uint8_t* ws = (uint8_t*)d_ws;
  bf16* x1b = (bf16*)(ws + 0);
  bf16* x2b = (bf16*)(ws + 8388608);
  bf16* AO  = (bf16*)(ws + 0);          // aliases x1b/x2b (dead after qkv_proj)
  bf16* Qws = (bf16*)(ws + 16777216);   // [b][h][s][64]
  bf16* Kws = (bf16*)(ws + 25165824);   // [b][h][s][64]
  bf16* Vtw = (bf16*)(ws + 33554432);   // [b][h][64][s]

  cast_x<<<4096, 256, 0, stream>>>(x1, x2, x1b);

  proj_kernel<0><<<dim3(64, 24), 256, 0, stream>>>(x1b, x2b, Wq, Wk, Wv, Qws, Kws, Vtw, nullptr);

  attn_kernel<<<256, 512, 0, stream>>>(Qws, Kws, Vtw, AO);

  proj_kernel<1><<<dim3(64, 8), 256, 0, stream>>>(AO, nullptr, Wo, nullptr, nullptr, d_out, nullptr, nullptr, bo);
}

// Round 10
// 103.192 us; speedup vs baseline: 1.6478x; 1.6478x over previous
//
#include <hip/hip_runtime.h>
#include <stdint.h>

typedef __bf16 bf16;
typedef __bf16 bf16x8 __attribute__((ext_vector_type(8)));
typedef __bf16 bf16x4 __attribute__((ext_vector_type(4)));
typedef float f32x4 __attribute__((ext_vector_type(4)));

#define MFMA16x16x32(A, B, C) __builtin_amdgcn_mfma_f32_16x16x32_bf16((A), (B), (C), 0, 0, 0)
#define SBAR() do { __builtin_amdgcn_s_barrier(); __builtin_amdgcn_sched_barrier(0); } while (0)

__device__ __forceinline__ void gload_lds16(const void* g, void* l) {
  __builtin_amdgcn_global_load_lds((const __attribute__((address_space(1))) void*)g,
                                   (__attribute__((address_space(3))) void*)l,
                                   16, 0, 0);
}

__device__ __forceinline__ float fexp2(float x) { return __builtin_amdgcn_exp2f(x); }

__device__ __forceinline__ bf16x8 cvt8(float4 a, float4 b) {
  bf16x8 o;
  o[0] = (bf16)a.x; o[1] = (bf16)a.y; o[2] = (bf16)a.z; o[3] = (bf16)a.w;
  o[4] = (bf16)b.x; o[5] = (bf16)b.y; o[6] = (bf16)b.z; o[7] = (bf16)b.w;
  return o;
}

// ---------------- x1+x2 -> bf16 (contiguous dst) ----------------
__global__ void cast_x(const float* __restrict__ x1, const float* __restrict__ x2,
                       bf16* __restrict__ out) {
  const size_t i = ((size_t)blockIdx.x * blockDim.x + threadIdx.x) * 8;
  const float* src = (i < 4194304) ? x1 + i : x2 + (i - 4194304);
  float4 a = *reinterpret_cast<const float4*>(src);
  float4 b = *reinterpret_cast<const float4*>(src + 4);
  *reinterpret_cast<bf16x8*>(out + i) = cvt8(a, b);
}

// ---------------- projection GEMM: C = A[M,512] @ W[N,512]^T ----------------
// (unchanged from r8 — validated)
template <int MODE>
__global__ __launch_bounds__(256, 4) void proj_kernel(
    const bf16* __restrict__ A0, const bf16* __restrict__ A1,
    const float* __restrict__ W0, const float* __restrict__ W1,
    const float* __restrict__ W2, void* __restrict__ C0, void* __restrict__ C1,
    void* __restrict__ C2, const float* __restrict__ bias) {
  __shared__ bf16 As[3][128 * 32];
  __shared__ bf16 Bs[2][64 * 32];
  const int tid = threadIdx.x;
  const int w = tid >> 6, l = tid & 63;
  const int wr = w >> 1, wc = w & 1;
  const int lr = l & 15, lg = l >> 4;
  const int bm = blockIdx.x, bn = blockIdx.y;
  const int K = 512;

  int sel = 0, wn = bn;
  const bf16* A;
  const float* Bf;
  if constexpr (MODE == 0) {
    sel = bn >> 3;
    wn = bn & 7;
    A = (sel == 0) ? A0 : A1;
    Bf = ((sel == 0) ? W0 : (sel == 1) ? W1 : W2) + (size_t)wn * 64 * K;
  } else {
    A = A0;
    Bf = W0 + (size_t)bn * 64 * K;
  }

  const int c_row = l >> 2;
  const int c_s = l & 3;
  const int sw = (c_s ^ (c_row & 3)) * 8;

  float4 lb[2][2];
  auto issue_A = [&](int t, int bb) {
#pragma unroll
    for (int i = 0; i < 2; i++) {
      const int q = w + i * 4;
      gload_lds16(A + (size_t)(bm * 128 + q * 16 + c_row) * K + t * 32 + sw, &As[bb][q * 512]);
    }
  };
  auto issue_B = [&](int t, int s) {
    const float* pb = Bf + (size_t)(w * 16 + c_row) * K + t * 32 + c_s * 8;
    lb[s][0] = *reinterpret_cast<const float4*>(pb);
    lb[s][1] = *reinterpret_cast<const float4*>(pb + 4);
  };
  auto commit_B = [&](int s, int bb) {
    *reinterpret_cast<bf16x8*>(&Bs[bb][w * 512 + c_row * 32 + sw]) = cvt8(lb[s][0], lb[s][1]);
  };

  f32x4 acc[4][2] = {};
  const int swz = (lr & 3) * 8;

  issue_A(0, 0); issue_B(0, 0);
  issue_A(1, 1); issue_B(1, 1);
  asm volatile("s_waitcnt vmcnt(4)" ::: "memory");
  commit_B(0, 0);
  asm volatile("s_waitcnt lgkmcnt(0)" ::: "memory");
  SBAR();

  const int NT = 16;
  for (int t = 0; t < NT; t++) {
    if (t + 2 < NT) { issue_A(t + 2, (t + 2) % 3); issue_B(t + 2, t & 1); }

    bf16x8 a[4], b[2];
    const int cur = t % 3;
#pragma unroll
    for (int mi = 0; mi < 4; mi++)
      a[mi] = *reinterpret_cast<const bf16x8*>(
          &As[cur][(wr * 64 + mi * 16 + lr) * 32 + (lg * 8 ^ swz)]);
#pragma unroll
    for (int ni = 0; ni < 2; ni++)
      b[ni] = *reinterpret_cast<const bf16x8*>(
          &Bs[t & 1][(wc * 32 + ni * 16 + lr) * 32 + (lg * 8 ^ swz)]);
#pragma unroll
    for (int mi = 0; mi < 4; mi++)
#pragma unroll
      for (int ni = 0; ni < 2; ni++)
        acc[mi][ni] = MFMA16x16x32(a[mi], b[ni], acc[mi][ni]);

    if (t + 1 < NT) {
      if (t + 2 < NT) asm volatile("s_waitcnt vmcnt(4)" ::: "memory");
      else            asm volatile("s_waitcnt vmcnt(0)" ::: "memory");
      commit_B((t + 1) & 1, (t + 1) & 1);
      asm volatile("s_waitcnt lgkmcnt(0)" ::: "memory");
      SBAR();
    }
  }

#pragma unroll
  for (int mi = 0; mi < 4; mi++) {
    const int m0 = bm * 128 + wr * 64 + mi * 16 + lg * 4;
#pragma unroll
    for (int ni = 0; ni < 2; ni++) {
      const int n = wc * 32 + ni * 16 + lr;
      if constexpr (MODE == 0) {
        const int gn = wn * 64 + n;
        if (sel < 2) {
          bf16* dst = (bf16*)((sel == 0) ? C0 : C1);
          const float scale = (sel == 0) ? 0.18033688011112f : 1.0f;
#pragma unroll
          for (int r = 0; r < 4; r++) {
            const int m = m0 + r;
            size_t d = (size_t)((m >> 11) * 8 + (gn >> 6)) * 131072 + (size_t)(m & 2047) * 64 + (gn & 63);
            dst[d] = (bf16)(acc[mi][ni][r] * scale);
          }
        } else {
          bf16x4 pv;
#pragma unroll
          for (int r = 0; r < 4; r++) pv[r] = (bf16)acc[mi][ni][r];
          size_t base = ((size_t)(m0 >> 11) * 512 + gn) * 2048 + (m0 & 2047);
          *reinterpret_cast<bf16x4*>((bf16*)C2 + base) = pv;
        }
      } else {
        const int gn = bn * 64 + n;
        const float bv = bias[gn];
#pragma unroll
        for (int r = 0; r < 4; r++)
          ((float*)C0)[(size_t)(m0 + r) * 512 + gn] = acc[mi][ni][r] + bv;
      }
    }
  }
}

// ---------------- flash attention (r7 structure, 2 blocks/CU, 3-buf ring) ----------------
// Q: [BH][2048][64] (pre-scaled by 0.125*log2e), K: [BH][2048][64], V^T: [BH][64][2048]
// Block: 256 thr (4 waves), 128 q-rows (32/wave), kv tiles of 64, grid 512 -> 2 blocks/CU.
// 3-buffer K/V ring, stage(t+2), steady-state vmcnt(4), single raw s_barrier per iter.
__global__ __launch_bounds__(256, 2) void attn_kernel(
    const bf16* __restrict__ Q, const bf16* __restrict__ Kk,
    const bf16* __restrict__ Vt, bf16* __restrict__ AO) {
  __shared__ bf16 Kb2[3][64 * 64];  // 24KB
  __shared__ bf16 Vb2[3][64 * 64];  // 24KB
  __shared__ bf16 Ps[4][32 * 64];   // 16KB per-wave P stash

  const int tid = threadIdx.x;
  const int w = tid >> 6, l = tid & 63;  // w 0..3
  const int lr = l & 15, lg = l >> 4;

  // XCD-aware decode: grid 512, lin&7 = XCD; 4 bh per XCD -> K/V L2-resident
  const int lin = blockIdx.x;  // 0..511
  const int xcd = lin & 7;
  const int m = lin >> 3;      // 0..63
  const int bh = xcd * 4 + (m & 3);
  const int qb = m >> 2;       // 0..15
  const int b = bh >> 3, h = bh & 7;

  const bf16* Qb = Q + (size_t)bh * 131072;
  const bf16* Kb = Kk + (size_t)bh * 131072;
  const bf16* Vb = Vt + (size_t)bh * 131072;

  const int q0 = qb * 128 + w * 32;

  // Q fragments (B-operand): qf[i]: col q = i*16+lr, k = d = ks*32+lg*8+j
  bf16x8 qf[2][2];
#pragma unroll
  for (int i = 0; i < 2; i++)
#pragma unroll
    for (int ks = 0; ks < 2; ks++)
      qf[i][ks] = *reinterpret_cast<const bf16x8*>(
          Qb + (size_t)(q0 + i * 16 + lr) * 64 + ks * 32 + lg * 8);

  // staging: chunk = 8 rows x 64 elems = 1KB; wave w stages chunks {2w,2w+1} of K and V
  const int crow = l >> 3;
  const int scol = ((l & 7) ^ crow) * 8;
  auto stage = [&](int kv0, int bb) {
#pragma unroll
    for (int i = 0; i < 2; i++) {
      const int ch = w * 2 + i;
      const int row = ch * 8 + crow;
      gload_lds16(Kb + (size_t)(kv0 + row) * 64 + scol, &Kb2[bb][ch * 512]);
      gload_lds16(Vb + (size_t)row * 2048 + kv0 + scol, &Vb2[bb][ch * 512]);
    }
  };

  f32x4 oacc[2][4] = {};
  float lsum[2] = {0.f, 0.f};
  const int sw8 = (lr & 7) * 8;

  stage(0, 0);
  stage(64, 1);
  asm volatile("s_waitcnt vmcnt(4)" ::: "memory");  // tile0 landed
  SBAR();

  for (int t = 0; t < 32; t++) {
    const int cur = t % 3;
    if (t + 2 < 32) stage((t + 2) * 64, (t + 2) % 3);

    // K fragments (shared across q-frags)
    bf16x8 kb[2][4];
#pragma unroll
    for (int ks = 0; ks < 2; ks++)
#pragma unroll
      for (int c = 0; c < 4; c++)
        kb[ks][c] = *reinterpret_cast<const bf16x8*>(
            &Kb2[cur][(c * 16 + lr) * 64 + ((ks * 32 + lg * 8) ^ sw8)]);

    // S^T = K Q^T per q-frag; exp2; stash P
#pragma unroll
    for (int i = 0; i < 2; i++) {
      f32x4 st[4] = {};
#pragma unroll
      for (int ks = 0; ks < 2; ks++)
#pragma unroll
        for (int c = 0; c < 4; c++)
          st[c] = MFMA16x16x32(kb[ks][c], qf[i][ks], st[c]);
#pragma unroll
      for (int c = 0; c < 4; c++) {
        float e0 = fexp2(st[c][0]);
        float e1 = fexp2(st[c][1]);
        float e2 = fexp2(st[c][2]);
        float e3 = fexp2(st[c][3]);
        lsum[i] += (e0 + e1) + (e2 + e3);
        bf16x4 pk;
        pk[0] = (bf16)e0; pk[1] = (bf16)e1; pk[2] = (bf16)e2; pk[3] = (bf16)e3;
        *reinterpret_cast<bf16x4*>(
            &Ps[w][(i * 16 + lr) * 64 + ((c * 16 + lg * 4) ^ sw8)]) = pk;
      }
    }

    // V fragments (shared across q-frags)
    bf16x8 vb[2][4];
#pragma unroll
    for (int ks = 0; ks < 2; ks++)
#pragma unroll
      for (int c = 0; c < 4; c++)
        vb[ks][c] = *reinterpret_cast<const bf16x8*>(
            &Vb2[cur][(c * 16 + lr) * 64 + ((ks * 32 + lg * 8) ^ sw8)]);

    // O += P @ V
#pragma unroll
    for (int i = 0; i < 2; i++)
#pragma unroll
      for (int ks = 0; ks < 2; ks++) {
        bf16x8 pa = *reinterpret_cast<const bf16x8*>(
            &Ps[w][(i * 16 + lr) * 64 + ((ks * 32 + lg * 8) ^ sw8)]);
#pragma unroll
        for (int c = 0; c < 4; c++)
          oacc[i][c] = MFMA16x16x32(pa, vb[ks][c], oacc[i][c]);
      }

    if (t < 30)       asm volatile("s_waitcnt vmcnt(4) lgkmcnt(0)" ::: "memory");
    else if (t == 30) asm volatile("s_waitcnt vmcnt(0) lgkmcnt(0)" ::: "memory");
    if (t < 31) SBAR();
  }

  // row-sum reduce: lanes lr, lr+16, lr+32, lr+48 hold partials of q-row i*16+lr
#pragma unroll
  for (int i = 0; i < 2; i++) {
    lsum[i] += __shfl_xor(lsum[i], 16);
    lsum[i] += __shfl_xor(lsum[i], 32);
  }

  // normalize + write AO[b*2048+q][h*64+d]; oacc row q = i*16 + lg*4 + r
#pragma unroll
  for (int i = 0; i < 2; i++) {
#pragma unroll
    for (int r = 0; r < 4; r++) {
      const float inv = 1.f / __shfl(lsum[i], lg * 4 + r);
      const int qrow = q0 + i * 16 + lg * 4 + r;
#pragma unroll
      for (int c = 0; c < 4; c++)
        AO[(size_t)(b * 2048 + qrow) * 512 + h * 64 + c * 16 + lr] = (bf16)(oacc[i][c][r] * inv);
    }
  }
}

// ---------------- launch ----------------
extern "C" void kernel_launch(void* const* d_in, const int* in_sizes, int n_in,
                              void* d_out, int out_size, void* d_ws, size_t ws_size,
                              hipStream_t stream) {
  (void)in_sizes; (void)n_in; (void)out_size; (void)ws_size;
  const float* x1 = (const float*)d_in[0];
  const float* x2 = (const float*)d_in[1];
  const float* Wq = (const float*)d_in[2];
  const float* Wk = (const float*)d_in[3];
  const float* Wv = (const float*)d_in[4];
  const float* Wo = (const float*)d_in[5];
  const float* bo = (const float*)d_in[6];

  uint8_t* ws = (uint8_t*)d_ws;
  bf16* x1b = (bf16*)(ws + 0);
  bf16* x2b = (bf16*)(ws + 8388608);
  bf16* AO  = (bf16*)(ws + 0);          // aliases x1b/x2b (dead after qkv_proj)
  bf16* Qws = (bf16*)(ws + 16777216);   // [b][h][s][64]
  bf16* Kws = (bf16*)(ws + 25165824);   // [b][h][s][64]
  bf16* Vtw = (bf16*)(ws + 33554432);   // [b][h][64][s]

  cast_x<<<4096, 256, 0, stream>>>(x1, x2, x1b);

  proj_kernel<0><<<dim3(64, 24), 256, 0, stream>>>(x1b, x2b, Wq, Wk, Wv, Qws, Kws, Vtw, nullptr);

  attn_kernel<<<512, 256, 0, stream>>>(Qws, Kws, Vtw, AO);

  proj_kernel<1><<<dim3(64, 8), 256, 0, stream>>>(AO, nullptr, Wo, nullptr, nullptr, d_out, nullptr, nullptr, bo);
}

// Round 11
// 103.078 us; speedup vs baseline: 1.6497x; 1.0011x over previous
//
#include <hip/hip_runtime.h>
#include <stdint.h>

typedef __bf16 bf16;
typedef __bf16 bf16x8 __attribute__((ext_vector_type(8)));
typedef __bf16 bf16x4 __attribute__((ext_vector_type(4)));
typedef float f32x4 __attribute__((ext_vector_type(4)));
typedef float f32x16 __attribute__((ext_vector_type(16)));
typedef uint32_t u32x4 __attribute__((ext_vector_type(4)));

#define MFMA16x16x32(A, B, C) __builtin_amdgcn_mfma_f32_16x16x32_bf16((A), (B), (C), 0, 0, 0)
#define MFMA32x32x16(A, B, C) __builtin_amdgcn_mfma_f32_32x32x16_bf16((A), (B), (C), 0, 0, 0)
#define SBAR() do { __builtin_amdgcn_s_barrier(); __builtin_amdgcn_sched_barrier(0); } while (0)

__device__ __forceinline__ void gload_lds16(const void* g, void* l) {
  __builtin_amdgcn_global_load_lds((const __attribute__((address_space(1))) void*)g,
                                   (__attribute__((address_space(3))) void*)l,
                                   16, 0, 0);
}

__device__ __forceinline__ float fexp2(float x) { return __builtin_amdgcn_exp2f(x); }

// pack two f32 -> one dword of 2 bf16 (lo = a, hi = b)
__device__ __forceinline__ uint32_t cvtpk(float a, float b) {
  uint32_t r;
  asm("v_cvt_pk_bf16_f32 %0, %1, %2" : "=v"(r) : "v"(a), "v"(b));
  return r;
}
// swap a's lanes 32-63 with b's lanes 0-31
__device__ __forceinline__ void plswap(uint32_t& a, uint32_t& b) {
  asm volatile("v_permlane32_swap_b32 %0, %1" : "+v"(a), "+v"(b));
}

__device__ __forceinline__ bf16x8 cvt8(float4 a, float4 b) {
  bf16x8 o;
  o[0] = (bf16)a.x; o[1] = (bf16)a.y; o[2] = (bf16)a.z; o[3] = (bf16)a.w;
  o[4] = (bf16)b.x; o[5] = (bf16)b.y; o[6] = (bf16)b.z; o[7] = (bf16)b.w;
  return o;
}

// ---------------- x1+x2 -> bf16 (contiguous dst) ----------------
__global__ void cast_x(const float* __restrict__ x1, const float* __restrict__ x2,
                       bf16* __restrict__ out) {
  const size_t i = ((size_t)blockIdx.x * blockDim.x + threadIdx.x) * 8;
  const float* src = (i < 4194304) ? x1 + i : x2 + (i - 4194304);
  float4 a = *reinterpret_cast<const float4*>(src);
  float4 b = *reinterpret_cast<const float4*>(src + 4);
  *reinterpret_cast<bf16x8*>(out + i) = cvt8(a, b);
}

// ---------------- projection GEMM: C = A[M,512] @ W[N,512]^T ----------------
// (unchanged from r10 — validated)
template <int MODE>
__global__ __launch_bounds__(256, 4) void proj_kernel(
    const bf16* __restrict__ A0, const bf16* __restrict__ A1,
    const float* __restrict__ W0, const float* __restrict__ W1,
    const float* __restrict__ W2, void* __restrict__ C0, void* __restrict__ C1,
    void* __restrict__ C2, const float* __restrict__ bias) {
  __shared__ bf16 As[3][128 * 32];
  __shared__ bf16 Bs[2][64 * 32];
  const int tid = threadIdx.x;
  const int w = tid >> 6, l = tid & 63;
  const int wr = w >> 1, wc = w & 1;
  const int lr = l & 15, lg = l >> 4;
  const int bm = blockIdx.x, bn = blockIdx.y;
  const int K = 512;

  int sel = 0, wn = bn;
  const bf16* A;
  const float* Bf;
  if constexpr (MODE == 0) {
    sel = bn >> 3;
    wn = bn & 7;
    A = (sel == 0) ? A0 : A1;
    Bf = ((sel == 0) ? W0 : (sel == 1) ? W1 : W2) + (size_t)wn * 64 * K;
  } else {
    A = A0;
    Bf = W0 + (size_t)bn * 64 * K;
  }

  const int c_row = l >> 2;
  const int c_s = l & 3;
  const int sw = (c_s ^ (c_row & 3)) * 8;

  float4 lb[2][2];
  auto issue_A = [&](int t, int bb) {
#pragma unroll
    for (int i = 0; i < 2; i++) {
      const int q = w + i * 4;
      gload_lds16(A + (size_t)(bm * 128 + q * 16 + c_row) * K + t * 32 + sw, &As[bb][q * 512]);
    }
  };
  auto issue_B = [&](int t, int s) {
    const float* pb = Bf + (size_t)(w * 16 + c_row) * K + t * 32 + c_s * 8;
    lb[s][0] = *reinterpret_cast<const float4*>(pb);
    lb[s][1] = *reinterpret_cast<const float4*>(pb + 4);
  };
  auto commit_B = [&](int s, int bb) {
    *reinterpret_cast<bf16x8*>(&Bs[bb][w * 512 + c_row * 32 + sw]) = cvt8(lb[s][0], lb[s][1]);
  };

  f32x4 acc[4][2] = {};
  const int swz = (lr & 3) * 8;

  issue_A(0, 0); issue_B(0, 0);
  issue_A(1, 1); issue_B(1, 1);
  asm volatile("s_waitcnt vmcnt(4)" ::: "memory");
  commit_B(0, 0);
  asm volatile("s_waitcnt lgkmcnt(0)" ::: "memory");
  SBAR();

  const int NT = 16;
  for (int t = 0; t < NT; t++) {
    if (t + 2 < NT) { issue_A(t + 2, (t + 2) % 3); issue_B(t + 2, t & 1); }

    bf16x8 a[4], b[2];
    const int cur = t % 3;
#pragma unroll
    for (int mi = 0; mi < 4; mi++)
      a[mi] = *reinterpret_cast<const bf16x8*>(
          &As[cur][(wr * 64 + mi * 16 + lr) * 32 + (lg * 8 ^ swz)]);
#pragma unroll
    for (int ni = 0; ni < 2; ni++)
      b[ni] = *reinterpret_cast<const bf16x8*>(
          &Bs[t & 1][(wc * 32 + ni * 16 + lr) * 32 + (lg * 8 ^ swz)]);
#pragma unroll
    for (int mi = 0; mi < 4; mi++)
#pragma unroll
      for (int ni = 0; ni < 2; ni++)
        acc[mi][ni] = MFMA16x16x32(a[mi], b[ni], acc[mi][ni]);

    if (t + 1 < NT) {
      if (t + 2 < NT) asm volatile("s_waitcnt vmcnt(4)" ::: "memory");
      else            asm volatile("s_waitcnt vmcnt(0)" ::: "memory");
      commit_B((t + 1) & 1, (t + 1) & 1);
      asm volatile("s_waitcnt lgkmcnt(0)" ::: "memory");
      SBAR();
    }
  }

#pragma unroll
  for (int mi = 0; mi < 4; mi++) {
    const int m0 = bm * 128 + wr * 64 + mi * 16 + lg * 4;
#pragma unroll
    for (int ni = 0; ni < 2; ni++) {
      const int n = wc * 32 + ni * 16 + lr;
      if constexpr (MODE == 0) {
        const int gn = wn * 64 + n;
        if (sel < 2) {
          bf16* dst = (bf16*)((sel == 0) ? C0 : C1);
          const float scale = (sel == 0) ? 0.18033688011112f : 1.0f;
#pragma unroll
          for (int r = 0; r < 4; r++) {
            const int m = m0 + r;
            size_t d = (size_t)((m >> 11) * 8 + (gn >> 6)) * 131072 + (size_t)(m & 2047) * 64 + (gn & 63);
            dst[d] = (bf16)(acc[mi][ni][r] * scale);
          }
        } else {
          bf16x4 pv;
#pragma unroll
          for (int r = 0; r < 4; r++) pv[r] = (bf16)acc[mi][ni][r];
          size_t base = ((size_t)(m0 >> 11) * 512 + gn) * 2048 + (m0 & 2047);
          *reinterpret_cast<bf16x4*>((bf16*)C2 + base) = pv;
        }
      } else {
        const int gn = bn * 64 + n;
        const float bv = bias[gn];
#pragma unroll
        for (int r = 0; r < 4; r++)
          ((float*)C0)[(size_t)(m0 + r) * 512 + gn] = acc[mi][ni][r] + bv;
      }
    }
  }
}

// ---------------- flash attention: 32x32 MFMA, in-register P (cvt_pk+permlane) --------
// Q: [BH][2048][64] (pre-scaled by 0.125*log2e), K: [BH][2048][64], V^T: [BH][64][2048]
// Block: 256 thr (4 waves), 128 q (32/wave), kv tiles 64, grid 512 = 2 blocks/CU.
// Swapped QK on 32x32x16: lane holds all S^T values of ONE q (col=l&31) -> lane-local
// softmax sum; P->PV A-frags via 16 cvt_pk + 8 permlane32_swap (no LDS round-trip).
// Per wave-iter: 16 ds_read_b128, 0 LDS writes (was 20R+8W with 16x16 path).
__global__ __launch_bounds__(256, 2) void attn_kernel(
    const bf16* __restrict__ Q, const bf16* __restrict__ Kk,
    const bf16* __restrict__ Vt, bf16* __restrict__ AO) {
  __shared__ bf16 Kb2[3][64 * 64];  // 24KB
  __shared__ bf16 Vb2[3][64 * 64];  // 24KB

  const int tid = threadIdx.x;
  const int w = tid >> 6, l = tid & 63;  // w 0..3
  const int q32 = l & 31;                // q-column owned by this lane
  const int h = l >> 5;                  // lane half

  // XCD-aware decode: grid 512, lin&7 = XCD; 4 bh per XCD -> K/V L2-resident
  const int lin = blockIdx.x;
  const int xcd = lin & 7;
  const int m = lin >> 3;
  const int bh = xcd * 4 + (m & 3);
  const int qb = m >> 2;  // 0..15
  const int b = bh >> 3, hd = bh & 7;

  const bf16* Qb = Q + (size_t)bh * 131072;
  const bf16* Kb = Kk + (size_t)bh * 131072;
  const bf16* Vb = Vt + (size_t)bh * 131072;

  const int q0 = qb * 128 + w * 32;

  // Q B-frags: col q = q32, k = d = ks*16 + h*8 + j
  bf16x8 qf[4];
#pragma unroll
  for (int ks = 0; ks < 4; ks++)
    qf[ks] = *reinterpret_cast<const bf16x8*>(
        Qb + (size_t)(q0 + q32) * 64 + ks * 16 + h * 8);

  // staging (identical to r10): chunk = 8 rows x 64; wave w stages chunks {2w,2w+1}
  const int crow = l >> 3;
  const int scol = ((l & 7) ^ crow) * 8;
  auto stage = [&](int kv0, int bb) {
#pragma unroll
    for (int i = 0; i < 2; i++) {
      const int ch = w * 2 + i;
      const int row = ch * 8 + crow;
      gload_lds16(Kb + (size_t)(kv0 + row) * 64 + scol, &Kb2[bb][ch * 512]);
      gload_lds16(Vb + (size_t)row * 2048 + kv0 + scol, &Vb2[bb][ch * 512]);
    }
  };

  f32x16 oacc[2] = {};
  float lsum = 0.f;
  const int l7 = l & 7;  // read-side swizzle key (row&7 == l&7 for our rows)

  stage(0, 0);
  stage(64, 1);
  asm volatile("s_waitcnt vmcnt(4)" ::: "memory");
  SBAR();

  for (int t = 0; t < 32; t++) {
    const int cur = t % 3;
    if (t + 2 < 32) stage((t + 2) * 64, (t + 2) % 3);

#pragma unroll
    for (int rb = 0; rb < 2; rb++) {
      // K A-frags: row kv = rb*32 + q32, k = d = ks*16 + h*8 + j
      bf16x8 kb[4];
#pragma unroll
      for (int ks = 0; ks < 4; ks++)
        kb[ks] = *reinterpret_cast<const bf16x8*>(
            &Kb2[cur][(rb * 32 + q32) * 64 + (((ks * 2 + h) ^ l7) * 8)]);

      // S^T = K Q^T: D col = q32, row kv_local = (r&3)+8*(r>>2)+4h (+32rb)
      f32x16 st = {};
#pragma unroll
      for (int ks = 0; ks < 4; ks++)
        st = MFMA32x32x16(kb[ks], qf[ks], st);

      // exp2 (fixed-max, log2-domain), lane-local sum, pack to bf16 dwords
      float e[16];
#pragma unroll
      for (int r = 0; r < 16; r++) {
        e[r] = fexp2(st[r]);
        lsum += e[r];
      }
      uint32_t Qp[8];
#pragma unroll
      for (int p = 0; p < 8; p++) Qp[p] = cvtpk(e[2 * p], e[2 * p + 1]);
      // relayout: A-frag needs kv = kst*16 + 8h + j; held kv = (r&3)+8*(r>>2)+4h.
      // swap(Q0,Q2) -> dwords j(0,1) & j(4,5) of kst0; swap(Q1,Q3) -> j(2,3) & j(6,7).
      plswap(Qp[0], Qp[2]);
      plswap(Qp[1], Qp[3]);
      plswap(Qp[4], Qp[6]);
      plswap(Qp[5], Qp[7]);
      const bf16x8 pa0 = __builtin_bit_cast(bf16x8, (u32x4){Qp[0], Qp[1], Qp[2], Qp[3]});
      const bf16x8 pa1 = __builtin_bit_cast(bf16x8, (u32x4){Qp[4], Qp[5], Qp[6], Qp[7]});

      // PV: B = V^T rows d = db*32+q32, k = kv = rb*32 + kst*16 + h*8 + j
#pragma unroll
      for (int kst = 0; kst < 2; kst++) {
        const bf16x8 pa = (kst == 0) ? pa0 : pa1;
#pragma unroll
        for (int db = 0; db < 2; db++) {
          bf16x8 vb = *reinterpret_cast<const bf16x8*>(
              &Vb2[cur][(db * 32 + q32) * 64 + (((rb * 4 + kst * 2 + h) ^ l7) * 8)]);
          oacc[db] = MFMA32x32x16(pa, vb, oacc[db]);
        }
      }
    }

    if (t < 30)       asm volatile("s_waitcnt vmcnt(4) lgkmcnt(0)" ::: "memory");
    else if (t == 30) asm volatile("s_waitcnt vmcnt(0) lgkmcnt(0)" ::: "memory");
    if (t < 31) SBAR();
  }

  // lanes l and l+32 hold partials of the same q
  lsum += __shfl_xor(lsum, 32);

  // normalize + write: oacc row q = (r&3)+8*(r>>2)+4h, col d = db*32+q32
  float inv[16];
#pragma unroll
  for (int r = 0; r < 16; r++) {
    const int qv = (r & 3) + 8 * (r >> 2) + 4 * h;
    inv[r] = 1.f / __shfl(lsum, qv);
  }
#pragma unroll
  for (int db = 0; db < 2; db++) {
#pragma unroll
    for (int r = 0; r < 16; r++) {
      const int qv = (r & 3) + 8 * (r >> 2) + 4 * h;
      AO[(size_t)(b * 2048 + q0 + qv) * 512 + hd * 64 + db * 32 + q32] =
          (bf16)(oacc[db][r] * inv[r]);
    }
  }
}

// ---------------- launch ----------------
extern "C" void kernel_launch(void* const* d_in, const int* in_sizes, int n_in,
                              void* d_out, int out_size, void* d_ws, size_t ws_size,
                              hipStream_t stream) {
  (void)in_sizes; (void)n_in; (void)out_size; (void)ws_size;
  const float* x1 = (const float*)d_in[0];
  const float* x2 = (const float*)d_in[1];
  const float* Wq = (const float*)d_in[2];
  const float* Wk = (const float*)d_in[3];
  const float* Wv = (const float*)d_in[4];
  const float* Wo = (const float*)d_in[5];
  const float* bo = (const float*)d_in[6];

  uint8_t* ws = (uint8_t*)d_ws;
  bf16* x1b = (bf16*)(ws + 0);
  bf16* x2b = (bf16*)(ws + 8388608);
  bf16* AO  = (bf16*)(ws + 0);          // aliases x1b/x2b (dead after qkv_proj)
  bf16* Qws = (bf16*)(ws + 16777216);   // [b][h][s][64]
  bf16* Kws = (bf16*)(ws + 25165824);   // [b][h][s][64]
  bf16* Vtw = (bf16*)(ws + 33554432);   // [b][h][64][s]

  cast_x<<<4096, 256, 0, stream>>>(x1, x2, x1b);

  proj_kernel<0><<<dim3(64, 24), 256, 0, stream>>>(x1b, x2b, Wq, Wk, Wv, Qws, Kws, Vtw, nullptr);

  attn_kernel<<<512, 256, 0, stream>>>(Qws, Kws, Vtw, AO);

  proj_kernel<1><<<dim3(64, 8), 256, 0, stream>>>(AO, nullptr, Wo, nullptr, nullptr, d_out, nullptr, nullptr, bo);
}